// Round 4
// baseline (216.754 us; speedup 1.0000x reference)
//
#include <hip/hip_runtime.h>

#define N_NODES 100000
#define N_EDGES 800000
#define SCAN_B 1024
#define SCAN_G ((N_NODES + SCAN_B - 1) / SCAN_B)   // 98 blocks
#define NBY    ((N_NODES + 255) / 256)             // 391
#define YBLK   (NBY * 4)                           // 1564 y-blocks
#define HBLK   ((N_EDGES + 255) / 256)             // 3125 hist-blocks
// Y layout: [n][kx][ky][o] bf16 (ushort), row = 16 o, plane = 256 per node (512 B)

__device__ __forceinline__ unsigned short f2bf(float f) {
    union { float f; unsigned u; } v; v.f = f;
    unsigned u = v.u;
    return (unsigned short)((u + 0x7FFFu + ((u >> 16) & 1u)) >> 16);  // RNE
}
__device__ __forceinline__ float bflo(unsigned u) {
    union { unsigned u; float f; } v; v.u = u << 16; return v.f;
}
__device__ __forceinline__ float bfhi(unsigned u) {
    union { unsigned u; float f; } v; v.u = u & 0xFFFF0000u; return v.f;
}

// ---- fused: y-transform blocks [0,YBLK) | hist blocks [YBLK, YBLK+HBLK) ----
// y: Y[n,k,o] = sum_i x[n,i] * W[k,i,o]   (bf16 store)
// hist: cnt[di] += 1 (fire-and-forget; no rank)
__global__ __launch_bounds__(256) void fused_y_hist(
    const float* __restrict__ x, const float* __restrict__ W,
    unsigned short* __restrict__ Y, const int* __restrict__ ei,
    const int* __restrict__ ej, int* __restrict__ cnt) {
    const int b = blockIdx.x;
    if (b < YBLK) {
        const int kbase = (b / NBY) * 4;
        const int n = (b % NBY) * 256 + threadIdx.x;
        if (n >= N_NODES) return;

        const float4* xv = (const float4*)(x + n * 16);
        float4 a = xv[0], bb = xv[1], c = xv[2], d = xv[3];
        float xr[16] = {a.x,a.y,a.z,a.w, bb.x,bb.y,bb.z,bb.w,
                        c.x,c.y,c.z,c.w, d.x,d.y,d.z,d.w};

        float acc[4][16];
#pragma unroll
        for (int kk = 0; kk < 4; ++kk)
#pragma unroll
            for (int o = 0; o < 16; ++o) acc[kk][o] = 0.f;

#pragma unroll
        for (int i = 0; i < 16; ++i) {
#pragma unroll
            for (int kk = 0; kk < 4; ++kk) {
                const float* wrow = W + ((kbase + kk) * 256 + i * 16);
#pragma unroll
                for (int o = 0; o < 16; ++o)
                    acc[kk][o] = fmaf(xr[i], wrow[o], acc[kk][o]);
            }
        }

        unsigned short* dst = Y + (size_t)n * 256 + kbase * 16;
#pragma unroll
        for (int kk = 0; kk < 4; ++kk) {
            unsigned pk[8];
#pragma unroll
            for (int q = 0; q < 8; ++q)
                pk[q] = (unsigned)f2bf(acc[kk][2*q]) | ((unsigned)f2bf(acc[kk][2*q+1]) << 16);
            uint4* p = (uint4*)(dst + kk * 16);
            p[0] = make_uint4(pk[0], pk[1], pk[2], pk[3]);
            p[1] = make_uint4(pk[4], pk[5], pk[6], pk[7]);
        }
    } else {
        const int e = (b - YBLK) * 256 + threadIdx.x;
        if (e >= N_EDGES) return;
        const int di = ei[e];
        if (di != ej[e]) atomicAdd(&cnt[di], 1);   // no return value used
    }
}

// phase 1: per-block exclusive scan of 1024 counts; emit block sums.
__global__ __launch_bounds__(1024) void scan1_kernel(
    const int* __restrict__ cnt, int* __restrict__ offs, int* __restrict__ bsum) {
    const int tid = threadIdx.x;
    const int i = blockIdx.x * SCAN_B + tid;
    int v = (i < N_NODES) ? cnt[i] : 0;
    const int lane = tid & 63, wv = tid >> 6;
    int inc = v;
#pragma unroll
    for (int off = 1; off < 64; off <<= 1) {
        int t2 = __shfl_up(inc, off);
        if (lane >= off) inc += t2;
    }
    __shared__ int wsum[16], woff[16];
    if (lane == 63) wsum[wv] = inc;
    __syncthreads();
    if (tid < 16) {
        int w = wsum[tid], iw = w;
#pragma unroll
        for (int off = 1; off < 16; off <<= 1) {
            int t2 = __shfl_up(iw, off, 16);
            if (tid >= off) iw += t2;
        }
        woff[tid] = iw - w;                       // exclusive wave offset
        if (tid == 15) bsum[blockIdx.x] = iw;     // block total
    }
    __syncthreads();
    if (i < N_NODES) offs[i] = woff[wv] + (inc - v);  // block-local exclusive
}

// phase 2+3 fused: each block wave-reduces its prefix over bsum, adds it,
// and mirrors the final offsets into cursor (scatter's atomic slot counters).
__global__ __launch_bounds__(1024) void scan23_kernel(
    const int* __restrict__ bsum, int* __restrict__ offs, int* __restrict__ cursor) {
    const int g = blockIdx.x;
    const int tid = threadIdx.x;
    __shared__ int sprefix;
    if (tid < 64) {
        int v = 0;
        if (tid < g) v = bsum[tid];
        if (tid + 64 < g) v += bsum[tid + 64];
#pragma unroll
        for (int off = 32; off >= 1; off >>= 1) v += __shfl_xor(v, off);
        if (tid == 0) {
            sprefix = v;
            if (g == SCAN_G - 1) offs[N_NODES] = v + bsum[g];  // grand total
        }
    }
    __syncthreads();
    const int p = sprefix;
    const int i = g * SCAN_B + tid;
    if (i < N_NODES) {
        int v = offs[i] + p;
        offs[i] = v;
        cursor[i] = v;
    }
}

// scatter: slot via returning atomic on cursor; one 16B meta per edge:
// {Y byte offset, w00|w01<<16, w10|w11<<16, 0}  (u16 fixed-point, unit S/65535)
__global__ __launch_bounds__(256) void scatter_kernel(
    const float* __restrict__ edge_attr, const int* __restrict__ ei,
    const int* __restrict__ ej, int* __restrict__ cursor,
    uint4* __restrict__ meta) {
    const int e = blockIdx.x * 256 + threadIdx.x;
    if (e >= N_EDGES) return;
    const int di = ei[e];
    const int sj = ej[e];
    if (di == sj) return;    // centerIgnore
    const float2 ea = ((const float2*)edge_attr)[e];

    float ux = fminf(fmaxf(ea.x, -1.f), 1.f);
    float uy = fminf(fmaxf(ea.y, -1.f), 1.f);
    float tx = (ux + 1.f) * 1.5f;
    float ty = (uy + 1.f) * 1.5f;
    int kx0 = min((int)tx, 2);
    int ky0 = min((int)ty, 2);
    float fx = tx - (float)kx0;
    float fy = ty - (float)ky0;
    // weights WITHOUT 1/128 (folded into gather's dequant constant)
    unsigned u00 = (unsigned)((1.f - fx) * (1.f - fy) * 65535.f + 0.5f);
    unsigned u01 = (unsigned)((1.f - fx) * fy * 65535.f + 0.5f);
    unsigned u10 = (unsigned)(fx * (1.f - fy) * 65535.f + 0.5f);
    unsigned u11 = (unsigned)(fx * fy * 65535.f + 0.5f);

    const int p = atomicAdd(&cursor[di], 1);
    meta[p] = make_uint4(sj * 512 + (kx0 * 4 + ky0) * 32,   // byte offset into Y
                         u00 | (u01 << 16), u10 | (u11 << 16), 0u);
}

// gather: 4 lanes per destination node; strided edges; shfl reduce; coalesced store.
__global__ __launch_bounds__(256) void gather_kernel(
    const int* __restrict__ offs, const uint4* __restrict__ meta,
    const unsigned short* __restrict__ Y, float* __restrict__ out) {
    const int g = blockIdx.x * 256 + threadIdx.x;
    const int n = g >> 2;
    const int l = g & 3;
    if (n >= N_NODES) return;
    const int s = offs[n];
    const int t = offs[n + 1];
    const char* Yb = (const char*)Y;
    const float WS = 1.f / (65535.f * 128.f);   // dequant * OUTPUT_SCALING

    float acc[16];
#pragma unroll
    for (int o = 0; o < 16; ++o) acc[o] = 0.f;

    for (int p = s + l; p < t; p += 4) {
        const uint4 m = meta[p];
        const float w00 = (float)(m.y & 0xFFFFu) * WS;
        const float w01 = (float)(m.y >> 16) * WS;
        const float w10 = (float)(m.z & 0xFFFFu) * WS;
        const float w11 = (float)(m.z >> 16) * WS;

        const uint4* pA = (const uint4*)(Yb + m.x);          // rows (kx0,ky0),(kx0,ky0+1)
        const uint4* pB = (const uint4*)(Yb + m.x + 128);    // rows (kx0+1,*)
        uint4 a0 = pA[0], a1 = pA[1], a2 = pA[2], a3 = pA[3];
        uint4 b0 = pB[0], b1 = pB[1], b2 = pB[2], b3 = pB[3];

        unsigned ra0[8] = {a0.x,a0.y,a0.z,a0.w, a1.x,a1.y,a1.z,a1.w};
        unsigned ra1[8] = {a2.x,a2.y,a2.z,a2.w, a3.x,a3.y,a3.z,a3.w};
        unsigned rb0[8] = {b0.x,b0.y,b0.z,b0.w, b1.x,b1.y,b1.z,b1.w};
        unsigned rb1[8] = {b2.x,b2.y,b2.z,b2.w, b3.x,b3.y,b3.z,b3.w};

#pragma unroll
        for (int q = 0; q < 8; ++q) {
            acc[2*q]   += bflo(ra0[q]) * w00 + bflo(ra1[q]) * w01
                        + bflo(rb0[q]) * w10 + bflo(rb1[q]) * w11;
            acc[2*q+1] += bfhi(ra0[q]) * w00 + bfhi(ra1[q]) * w01
                        + bfhi(rb0[q]) * w10 + bfhi(rb1[q]) * w11;
        }
    }

    // reduce across the 4-lane group (xor 1, xor 2 stay inside the group)
#pragma unroll
    for (int o = 0; o < 16; ++o) {
        acc[o] += __shfl_xor(acc[o], 1);
        acc[o] += __shfl_xor(acc[o], 2);
    }

    // coalesced store: lane l writes float4 quarter l (constant indices only)
    float4 vq;
    if      (l == 0) vq = make_float4(acc[0],  acc[1],  acc[2],  acc[3]);
    else if (l == 1) vq = make_float4(acc[4],  acc[5],  acc[6],  acc[7]);
    else if (l == 2) vq = make_float4(acc[8],  acc[9],  acc[10], acc[11]);
    else             vq = make_float4(acc[12], acc[13], acc[14], acc[15]);
    ((float4*)(out + (size_t)n * 16))[l] = vq;
}

// ---------------- fallback: atomic-scatter version (needs only Y) ----------------
__global__ __launch_bounds__(256) void edge_kernel(
    const float* __restrict__ edge_attr, const int* __restrict__ ei,
    const int* __restrict__ ej, const unsigned short* __restrict__ Y,
    float* __restrict__ out) {
    const int e = blockIdx.x * 256 + threadIdx.x;
    if (e >= N_EDGES) return;
    const int di = ei[e];
    const int sj = ej[e];
    const float2 ea = ((const float2*)edge_attr)[e];
    if (di == sj) return;

    float ux = fminf(fmaxf(ea.x, -1.f), 1.f);
    float uy = fminf(fmaxf(ea.y, -1.f), 1.f);
    float tx = (ux + 1.f) * 1.5f;
    float ty = (uy + 1.f) * 1.5f;
    int kx0 = min((int)tx, 2);
    int ky0 = min((int)ty, 2);
    float fx = tx - (float)kx0;
    float fy = ty - (float)ky0;
    const float S = 1.f / 128.f;
    float w00 = (1.f - fx) * (1.f - fy) * S;
    float w01 = (1.f - fx) * fy * S;
    float w10 = fx * (1.f - fy) * S;
    float w11 = fx * fy * S;

    const unsigned short* base = Y + (size_t)sj * 256 + (kx0 * 4 + ky0) * 16;
    const uint4* pA = (const uint4*)base;
    const uint4* pB = (const uint4*)(base + 64);
    uint4 a0 = pA[0], a1 = pA[1], a2 = pA[2], a3 = pA[3];
    uint4 b0 = pB[0], b1 = pB[1], b2 = pB[2], b3 = pB[3];

    unsigned ra0[8] = {a0.x,a0.y,a0.z,a0.w, a1.x,a1.y,a1.z,a1.w};
    unsigned ra1[8] = {a2.x,a2.y,a2.z,a2.w, a3.x,a3.y,a3.z,a3.w};
    unsigned rb0[8] = {b0.x,b0.y,b0.z,b0.w, b1.x,b1.y,b1.z,b1.w};
    unsigned rb1[8] = {b2.x,b2.y,b2.z,b2.w, b3.x,b3.y,b3.z,b3.w};

    float* o16 = out + (size_t)di * 16;
#pragma unroll
    for (int q = 0; q < 8; ++q) {
        float m0 = bflo(ra0[q]) * w00 + bflo(ra1[q]) * w01
                 + bflo(rb0[q]) * w10 + bflo(rb1[q]) * w11;
        float m1 = bfhi(ra0[q]) * w00 + bfhi(ra1[q]) * w01
                 + bfhi(rb0[q]) * w10 + bfhi(rb1[q]) * w11;
        atomicAdd(o16 + 2 * q, m0);
        atomicAdd(o16 + 2 * q + 1, m1);
    }
}

__global__ __launch_bounds__(256) void y_only_kernel(
    const float* __restrict__ x, const float* __restrict__ W,
    unsigned short* __restrict__ Y) {
    const int n = blockIdx.x * 256 + threadIdx.x;
    const int kbase = blockIdx.y * 4;
    if (n >= N_NODES) return;
    const float4* xv = (const float4*)(x + n * 16);
    float4 a = xv[0], b = xv[1], c = xv[2], d = xv[3];
    float xr[16] = {a.x,a.y,a.z,a.w, b.x,b.y,b.z,b.w,
                    c.x,c.y,c.z,c.w, d.x,d.y,d.z,d.w};
    float acc[4][16];
#pragma unroll
    for (int kk = 0; kk < 4; ++kk)
#pragma unroll
        for (int o = 0; o < 16; ++o) acc[kk][o] = 0.f;
#pragma unroll
    for (int i = 0; i < 16; ++i)
#pragma unroll
        for (int kk = 0; kk < 4; ++kk) {
            const float* wrow = W + ((kbase + kk) * 256 + i * 16);
#pragma unroll
            for (int o = 0; o < 16; ++o)
                acc[kk][o] = fmaf(xr[i], wrow[o], acc[kk][o]);
        }
    unsigned short* dst = Y + (size_t)n * 256 + kbase * 16;
#pragma unroll
    for (int kk = 0; kk < 4; ++kk) {
        unsigned pk[8];
#pragma unroll
        for (int q = 0; q < 8; ++q)
            pk[q] = (unsigned)f2bf(acc[kk][2*q]) | ((unsigned)f2bf(acc[kk][2*q+1]) << 16);
        uint4* p = (uint4*)(dst + kk * 16);
        p[0] = make_uint4(pk[0], pk[1], pk[2], pk[3]);
        p[1] = make_uint4(pk[4], pk[5], pk[6], pk[7]);
    }
}

// last-resort fallback: per-edge direct compute
__global__ __launch_bounds__(256) void edge_direct(
    const float* __restrict__ x, const float* __restrict__ edge_attr,
    const float* __restrict__ W, const int* __restrict__ ei,
    const int* __restrict__ ej, float* __restrict__ out) {
    const int e = blockIdx.x * 256 + threadIdx.x;
    if (e >= N_EDGES) return;
    const int di = ei[e];
    const int sj = ej[e];
    const float2 ea = ((const float2*)edge_attr)[e];
    if (di == sj) return;

    float ux = fminf(fmaxf(ea.x, -1.f), 1.f);
    float uy = fminf(fmaxf(ea.y, -1.f), 1.f);
    float tx = (ux + 1.f) * 1.5f, ty = (uy + 1.f) * 1.5f;
    int kx0 = min((int)tx, 2), ky0 = min((int)ty, 2);
    float fx = tx - (float)kx0, fy = ty - (float)ky0;
    const float S = 1.f / 128.f;
    float wgt[4] = {(1.f-fx)*(1.f-fy)*S, (1.f-fx)*fy*S, fx*(1.f-fy)*S, fx*fy*S};
    int kidx[4] = {kx0*4+ky0, kx0*4+ky0+1, (kx0+1)*4+ky0, (kx0+1)*4+ky0+1};

    const float* xj = x + (size_t)sj * 16;
    float xr[16];
#pragma unroll
    for (int i = 0; i < 16; ++i) xr[i] = xj[i];

    float msg[16];
#pragma unroll
    for (int o = 0; o < 16; ++o) msg[o] = 0.f;
#pragma unroll
    for (int p = 0; p < 4; ++p) {
        const float* wk = W + kidx[p] * 256;
#pragma unroll
        for (int i = 0; i < 16; ++i) {
            float xw = xr[i] * wgt[p];
#pragma unroll
            for (int o = 0; o < 16; ++o)
                msg[o] = fmaf(xw, wk[i * 16 + o], msg[o]);
        }
    }
    float* o16 = out + (size_t)di * 16;
#pragma unroll
    for (int o = 0; o < 16; ++o) atomicAdd(o16 + o, msg[o]);
}

extern "C" void kernel_launch(void* const* d_in, const int* in_sizes, int n_in,
                              void* d_out, int out_size, void* d_ws, size_t ws_size,
                              hipStream_t stream) {
    const float* x         = (const float*)d_in[0];
    const float* edge_attr = (const float*)d_in[1];
    const float* W         = (const float*)d_in[2];
    const int*   ei        = (const int*)d_in[3];
    const int*   ej        = (const int*)d_in[4];
    float* out = (float*)d_out;

    // workspace layout (16B aligned)
    const size_t oY    = 0;                                 // 51,200,000
    const size_t oCnt  = oY + (size_t)N_NODES * 512;        // 400,000
    const size_t oOffs = oCnt + 400000;                     // 400,016 (N+1 ints, padded)
    const size_t oCur  = oOffs + 400016;                    // 400,000
    const size_t oBsum = oCur + 400000;                     // 512
    const size_t oMeta = oBsum + 512;                       // 12,800,000
    const size_t total = oMeta + (size_t)N_EDGES * 16;      // ~65.2 MB

    char* ws = (char*)d_ws;
    const size_t yBytes = (size_t)N_NODES * 512;

    if (ws_size >= total) {
        unsigned short* Y = (unsigned short*)(ws + oY);
        int*   cnt    = (int*)(ws + oCnt);
        int*   offs   = (int*)(ws + oOffs);
        int*   cursor = (int*)(ws + oCur);
        int*   bsum   = (int*)(ws + oBsum);
        uint4* meta   = (uint4*)(ws + oMeta);

        hipMemsetAsync(cnt, 0, (size_t)N_NODES * 4, stream);
        fused_y_hist<<<YBLK + HBLK, 256, 0, stream>>>(x, W, Y, ei, ej, cnt);
        scan1_kernel<<<SCAN_G, SCAN_B, 0, stream>>>(cnt, offs, bsum);
        scan23_kernel<<<SCAN_G, SCAN_B, 0, stream>>>(bsum, offs, cursor);
        scatter_kernel<<<HBLK, 256, 0, stream>>>(edge_attr, ei, ej, cursor, meta);
        gather_kernel<<<(4 * N_NODES + 255) / 256, 256, 0, stream>>>(offs, meta, Y, out);
    } else if (ws_size >= yBytes) {
        hipMemsetAsync(d_out, 0, (size_t)out_size * sizeof(float), stream);
        unsigned short* Y = (unsigned short*)d_ws;
        dim3 gA(NBY, 4);
        y_only_kernel<<<gA, 256, 0, stream>>>(x, W, Y);
        edge_kernel<<<HBLK, 256, 0, stream>>>(edge_attr, ei, ej, Y, out);
    } else {
        hipMemsetAsync(d_out, 0, (size_t)out_size * sizeof(float), stream);
        edge_direct<<<HBLK, 256, 0, stream>>>(x, edge_attr, W, ei, ej, out);
    }
}

// Round 5
// 186.727 us; speedup vs baseline: 1.1608x; 1.1608x over previous
//
#include <hip/hip_runtime.h>

#define N_NODES 100000
#define N_EDGES 800000
#define SCAN_B 1024
#define SCAN_G ((N_NODES + SCAN_B - 1) / SCAN_B)   // 98 blocks
#define NBY    ((N_NODES + 255) / 256)             // 391
#define YBLK   (NBY * 4)                           // 1564 y-blocks
#define HBLK   ((N_EDGES + 255) / 256)             // 3125 hist-blocks
// Y layout: [n][kx][ky][o] bf16 (ushort), row = 16 o, plane = 256 per node (512 B)

__device__ __forceinline__ unsigned short f2bf(float f) {
    union { float f; unsigned u; } v; v.f = f;
    unsigned u = v.u;
    return (unsigned short)((u + 0x7FFFu + ((u >> 16) & 1u)) >> 16);  // RNE
}
__device__ __forceinline__ float bflo(unsigned u) {
    union { unsigned u; float f; } v; v.u = u << 16; return v.f;
}
__device__ __forceinline__ float bfhi(unsigned u) {
    union { unsigned u; float f; } v; v.u = u & 0xFFFF0000u; return v.f;
}

// ---- fused: y-transform blocks [0,YBLK) | hist blocks [YBLK, YBLK+HBLK) ----
// y: Y[n,k,o] = sum_i x[n,i] * W[k,i,o]   (bf16 store)
// hist: rank[e] = cnt[di]++ (returning atomic; rank stored coalesced e-indexed)
__global__ __launch_bounds__(256) void fused_y_hist(
    const float* __restrict__ x, const float* __restrict__ W,
    unsigned short* __restrict__ Y, const int* __restrict__ ei,
    const int* __restrict__ ej, int* __restrict__ cnt, int* __restrict__ rank) {
    const int b = blockIdx.x;
    if (b < YBLK) {
        const int kbase = (b / NBY) * 4;
        const int n = (b % NBY) * 256 + threadIdx.x;
        if (n >= N_NODES) return;

        const float4* xv = (const float4*)(x + n * 16);
        float4 a = xv[0], bb = xv[1], c = xv[2], d = xv[3];
        float xr[16] = {a.x,a.y,a.z,a.w, bb.x,bb.y,bb.z,bb.w,
                        c.x,c.y,c.z,c.w, d.x,d.y,d.z,d.w};

        float acc[4][16];
#pragma unroll
        for (int kk = 0; kk < 4; ++kk)
#pragma unroll
            for (int o = 0; o < 16; ++o) acc[kk][o] = 0.f;

#pragma unroll
        for (int i = 0; i < 16; ++i) {
#pragma unroll
            for (int kk = 0; kk < 4; ++kk) {
                const float* wrow = W + ((kbase + kk) * 256 + i * 16);
#pragma unroll
                for (int o = 0; o < 16; ++o)
                    acc[kk][o] = fmaf(xr[i], wrow[o], acc[kk][o]);
            }
        }

        unsigned short* dst = Y + (size_t)n * 256 + kbase * 16;
#pragma unroll
        for (int kk = 0; kk < 4; ++kk) {
            unsigned pk[8];
#pragma unroll
            for (int q = 0; q < 8; ++q)
                pk[q] = (unsigned)f2bf(acc[kk][2*q]) | ((unsigned)f2bf(acc[kk][2*q+1]) << 16);
            uint4* p = (uint4*)(dst + kk * 16);
            p[0] = make_uint4(pk[0], pk[1], pk[2], pk[3]);
            p[1] = make_uint4(pk[4], pk[5], pk[6], pk[7]);
        }
    } else {
        const int e = (b - YBLK) * 256 + threadIdx.x;
        if (e >= N_EDGES) return;
        const int di = ei[e];
        if (di == ej[e]) { rank[e] = -1; return; }   // centerIgnore
        rank[e] = atomicAdd(&cnt[di], 1);
    }
}

// phase 1: per-block exclusive scan of 1024 counts; emit block sums.
__global__ __launch_bounds__(1024) void scan1_kernel(
    const int* __restrict__ cnt, int* __restrict__ offs, int* __restrict__ bsum) {
    const int tid = threadIdx.x;
    const int i = blockIdx.x * SCAN_B + tid;
    int v = (i < N_NODES) ? cnt[i] : 0;
    const int lane = tid & 63, wv = tid >> 6;
    int inc = v;
#pragma unroll
    for (int off = 1; off < 64; off <<= 1) {
        int t2 = __shfl_up(inc, off);
        if (lane >= off) inc += t2;
    }
    __shared__ int wsum[16], woff[16];
    if (lane == 63) wsum[wv] = inc;
    __syncthreads();
    if (tid < 16) {
        int w = wsum[tid], iw = w;
#pragma unroll
        for (int off = 1; off < 16; off <<= 1) {
            int t2 = __shfl_up(iw, off, 16);
            if (tid >= off) iw += t2;
        }
        woff[tid] = iw - w;                       // exclusive wave offset
        if (tid == 15) bsum[blockIdx.x] = iw;     // block total
    }
    __syncthreads();
    if (i < N_NODES) offs[i] = woff[wv] + (inc - v);  // block-local exclusive
}

// phase 2+3 fused: each block wave-reduces its prefix over bsum and adds it.
__global__ __launch_bounds__(1024) void scan23_kernel(
    const int* __restrict__ bsum, int* __restrict__ offs) {
    const int g = blockIdx.x;
    const int tid = threadIdx.x;
    __shared__ int sprefix;
    if (tid < 64) {
        int v = 0;
        if (tid < g) v = bsum[tid];
        if (tid + 64 < g) v += bsum[tid + 64];
#pragma unroll
        for (int off = 32; off >= 1; off >>= 1) v += __shfl_xor(v, off);
        if (tid == 0) {
            sprefix = v;
            if (g == SCAN_G - 1) offs[N_NODES] = v + bsum[g];  // grand total
        }
    }
    __syncthreads();
    const int i = g * SCAN_B + tid;
    if (i < N_NODES) offs[i] += sprefix;
}

// scatter: atomic-free; slot = offs[di] + rank[e]; one 16B meta per edge:
// {Y byte offset, w00|w01<<16, w10|w11<<16, 0}  (u16 fixed-point)
__global__ __launch_bounds__(256) void scatter_kernel(
    const float* __restrict__ edge_attr, const int* __restrict__ ei,
    const int* __restrict__ ej, const int* __restrict__ offs,
    const int* __restrict__ rank, uint4* __restrict__ meta) {
    const int e = blockIdx.x * 256 + threadIdx.x;
    if (e >= N_EDGES) return;
    const int r = rank[e];
    if (r < 0) return;    // centerIgnore
    const int di = ei[e];
    const int sj = ej[e];
    const float2 ea = ((const float2*)edge_attr)[e];

    float ux = fminf(fmaxf(ea.x, -1.f), 1.f);
    float uy = fminf(fmaxf(ea.y, -1.f), 1.f);
    float tx = (ux + 1.f) * 1.5f;
    float ty = (uy + 1.f) * 1.5f;
    int kx0 = min((int)tx, 2);
    int ky0 = min((int)ty, 2);
    float fx = tx - (float)kx0;
    float fy = ty - (float)ky0;
    // weights WITHOUT 1/128 (folded into gather's dequant constant)
    unsigned u00 = (unsigned)((1.f - fx) * (1.f - fy) * 65535.f + 0.5f);
    unsigned u01 = (unsigned)((1.f - fx) * fy * 65535.f + 0.5f);
    unsigned u10 = (unsigned)(fx * (1.f - fy) * 65535.f + 0.5f);
    unsigned u11 = (unsigned)(fx * fy * 65535.f + 0.5f);

    const int p = offs[di] + r;
    meta[p] = make_uint4(sj * 512 + (kx0 * 4 + ky0) * 32,   // byte offset into Y
                         u00 | (u01 << 16), u10 | (u11 << 16), 0u);
}

// gather: 4 lanes per destination node; strided edges; shfl reduce; coalesced store.
__global__ __launch_bounds__(256) void gather_kernel(
    const int* __restrict__ offs, const uint4* __restrict__ meta,
    const unsigned short* __restrict__ Y, float* __restrict__ out) {
    const int g = blockIdx.x * 256 + threadIdx.x;
    const int n = g >> 2;
    const int l = g & 3;
    if (n >= N_NODES) return;
    const int s = offs[n];
    const int t = offs[n + 1];
    const char* Yb = (const char*)Y;
    const float WS = 1.f / (65535.f * 128.f);   // dequant * OUTPUT_SCALING

    float acc[16];
#pragma unroll
    for (int o = 0; o < 16; ++o) acc[o] = 0.f;

    for (int p = s + l; p < t; p += 4) {
        const uint4 m = meta[p];
        const float w00 = (float)(m.y & 0xFFFFu) * WS;
        const float w01 = (float)(m.y >> 16) * WS;
        const float w10 = (float)(m.z & 0xFFFFu) * WS;
        const float w11 = (float)(m.z >> 16) * WS;

        const uint4* pA = (const uint4*)(Yb + m.x);          // rows (kx0,ky0),(kx0,ky0+1)
        const uint4* pB = (const uint4*)(Yb + m.x + 128);    // rows (kx0+1,*)
        uint4 a0 = pA[0], a1 = pA[1], a2 = pA[2], a3 = pA[3];
        uint4 b0 = pB[0], b1 = pB[1], b2 = pB[2], b3 = pB[3];

        unsigned ra0[8] = {a0.x,a0.y,a0.z,a0.w, a1.x,a1.y,a1.z,a1.w};
        unsigned ra1[8] = {a2.x,a2.y,a2.z,a2.w, a3.x,a3.y,a3.z,a3.w};
        unsigned rb0[8] = {b0.x,b0.y,b0.z,b0.w, b1.x,b1.y,b1.z,b1.w};
        unsigned rb1[8] = {b2.x,b2.y,b2.z,b2.w, b3.x,b3.y,b3.z,b3.w};

#pragma unroll
        for (int q = 0; q < 8; ++q) {
            acc[2*q]   += bflo(ra0[q]) * w00 + bflo(ra1[q]) * w01
                        + bflo(rb0[q]) * w10 + bflo(rb1[q]) * w11;
            acc[2*q+1] += bfhi(ra0[q]) * w00 + bfhi(ra1[q]) * w01
                        + bfhi(rb0[q]) * w10 + bfhi(rb1[q]) * w11;
        }
    }

    // reduce across the 4-lane group (xor 1, xor 2 stay inside the group)
#pragma unroll
    for (int o = 0; o < 16; ++o) {
        acc[o] += __shfl_xor(acc[o], 1);
        acc[o] += __shfl_xor(acc[o], 2);
    }

    // coalesced store: lane l writes float4 quarter l (constant indices only)
    float4 vq;
    if      (l == 0) vq = make_float4(acc[0],  acc[1],  acc[2],  acc[3]);
    else if (l == 1) vq = make_float4(acc[4],  acc[5],  acc[6],  acc[7]);
    else if (l == 2) vq = make_float4(acc[8],  acc[9],  acc[10], acc[11]);
    else             vq = make_float4(acc[12], acc[13], acc[14], acc[15]);
    ((float4*)(out + (size_t)n * 16))[l] = vq;
}

// ---------------- fallback: atomic-scatter version (needs only Y) ----------------
__global__ __launch_bounds__(256) void edge_kernel(
    const float* __restrict__ edge_attr, const int* __restrict__ ei,
    const int* __restrict__ ej, const unsigned short* __restrict__ Y,
    float* __restrict__ out) {
    const int e = blockIdx.x * 256 + threadIdx.x;
    if (e >= N_EDGES) return;
    const int di = ei[e];
    const int sj = ej[e];
    const float2 ea = ((const float2*)edge_attr)[e];
    if (di == sj) return;

    float ux = fminf(fmaxf(ea.x, -1.f), 1.f);
    float uy = fminf(fmaxf(ea.y, -1.f), 1.f);
    float tx = (ux + 1.f) * 1.5f;
    float ty = (uy + 1.f) * 1.5f;
    int kx0 = min((int)tx, 2);
    int ky0 = min((int)ty, 2);
    float fx = tx - (float)kx0;
    float fy = ty - (float)ky0;
    const float S = 1.f / 128.f;
    float w00 = (1.f - fx) * (1.f - fy) * S;
    float w01 = (1.f - fx) * fy * S;
    float w10 = fx * (1.f - fy) * S;
    float w11 = fx * fy * S;

    const unsigned short* base = Y + (size_t)sj * 256 + (kx0 * 4 + ky0) * 16;
    const uint4* pA = (const uint4*)base;
    const uint4* pB = (const uint4*)(base + 64);
    uint4 a0 = pA[0], a1 = pA[1], a2 = pA[2], a3 = pA[3];
    uint4 b0 = pB[0], b1 = pB[1], b2 = pB[2], b3 = pB[3];

    unsigned ra0[8] = {a0.x,a0.y,a0.z,a0.w, a1.x,a1.y,a1.z,a1.w};
    unsigned ra1[8] = {a2.x,a2.y,a2.z,a2.w, a3.x,a3.y,a3.z,a3.w};
    unsigned rb0[8] = {b0.x,b0.y,b0.z,b0.w, b1.x,b1.y,b1.z,b1.w};
    unsigned rb1[8] = {b2.x,b2.y,b2.z,b2.w, b3.x,b3.y,b3.z,b3.w};

    float* o16 = out + (size_t)di * 16;
#pragma unroll
    for (int q = 0; q < 8; ++q) {
        float m0 = bflo(ra0[q]) * w00 + bflo(ra1[q]) * w01
                 + bflo(rb0[q]) * w10 + bflo(rb1[q]) * w11;
        float m1 = bfhi(ra0[q]) * w00 + bfhi(ra1[q]) * w01
                 + bfhi(rb0[q]) * w10 + bfhi(rb1[q]) * w11;
        atomicAdd(o16 + 2 * q, m0);
        atomicAdd(o16 + 2 * q + 1, m1);
    }
}

__global__ __launch_bounds__(256) void y_only_kernel(
    const float* __restrict__ x, const float* __restrict__ W,
    unsigned short* __restrict__ Y) {
    const int n = blockIdx.x * 256 + threadIdx.x;
    const int kbase = blockIdx.y * 4;
    if (n >= N_NODES) return;
    const float4* xv = (const float4*)(x + n * 16);
    float4 a = xv[0], b = xv[1], c = xv[2], d = xv[3];
    float xr[16] = {a.x,a.y,a.z,a.w, b.x,b.y,b.z,b.w,
                    c.x,c.y,c.z,c.w, d.x,d.y,d.z,d.w};
    float acc[4][16];
#pragma unroll
    for (int kk = 0; kk < 4; ++kk)
#pragma unroll
        for (int o = 0; o < 16; ++o) acc[kk][o] = 0.f;
#pragma unroll
    for (int i = 0; i < 16; ++i)
#pragma unroll
        for (int kk = 0; kk < 4; ++kk) {
            const float* wrow = W + ((kbase + kk) * 256 + i * 16);
#pragma unroll
            for (int o = 0; o < 16; ++o)
                acc[kk][o] = fmaf(xr[i], wrow[o], acc[kk][o]);
        }
    unsigned short* dst = Y + (size_t)n * 256 + kbase * 16;
#pragma unroll
    for (int kk = 0; kk < 4; ++kk) {
        unsigned pk[8];
#pragma unroll
        for (int q = 0; q < 8; ++q)
            pk[q] = (unsigned)f2bf(acc[kk][2*q]) | ((unsigned)f2bf(acc[kk][2*q+1]) << 16);
        uint4* p = (uint4*)(dst + kk * 16);
        p[0] = make_uint4(pk[0], pk[1], pk[2], pk[3]);
        p[1] = make_uint4(pk[4], pk[5], pk[6], pk[7]);
    }
}

// last-resort fallback: per-edge direct compute
__global__ __launch_bounds__(256) void edge_direct(
    const float* __restrict__ x, const float* __restrict__ edge_attr,
    const float* __restrict__ W, const int* __restrict__ ei,
    const int* __restrict__ ej, float* __restrict__ out) {
    const int e = blockIdx.x * 256 + threadIdx.x;
    if (e >= N_EDGES) return;
    const int di = ei[e];
    const int sj = ej[e];
    const float2 ea = ((const float2*)edge_attr)[e];
    if (di == sj) return;

    float ux = fminf(fmaxf(ea.x, -1.f), 1.f);
    float uy = fminf(fmaxf(ea.y, -1.f), 1.f);
    float tx = (ux + 1.f) * 1.5f, ty = (uy + 1.f) * 1.5f;
    int kx0 = min((int)tx, 2), ky0 = min((int)ty, 2);
    float fx = tx - (float)kx0, fy = ty - (float)ky0;
    const float S = 1.f / 128.f;
    float wgt[4] = {(1.f-fx)*(1.f-fy)*S, (1.f-fx)*fy*S, fx*(1.f-fy)*S, fx*fy*S};
    int kidx[4] = {kx0*4+ky0, kx0*4+ky0+1, (kx0+1)*4+ky0, (kx0+1)*4+ky0+1};

    const float* xj = x + (size_t)sj * 16;
    float xr[16];
#pragma unroll
    for (int i = 0; i < 16; ++i) xr[i] = xj[i];

    float msg[16];
#pragma unroll
    for (int o = 0; o < 16; ++o) msg[o] = 0.f;
#pragma unroll
    for (int p = 0; p < 4; ++p) {
        const float* wk = W + kidx[p] * 256;
#pragma unroll
        for (int i = 0; i < 16; ++i) {
            float xw = xr[i] * wgt[p];
#pragma unroll
            for (int o = 0; o < 16; ++o)
                msg[o] = fmaf(xw, wk[i * 16 + o], msg[o]);
        }
    }
    float* o16 = out + (size_t)di * 16;
#pragma unroll
    for (int o = 0; o < 16; ++o) atomicAdd(o16 + o, msg[o]);
}

extern "C" void kernel_launch(void* const* d_in, const int* in_sizes, int n_in,
                              void* d_out, int out_size, void* d_ws, size_t ws_size,
                              hipStream_t stream) {
    const float* x         = (const float*)d_in[0];
    const float* edge_attr = (const float*)d_in[1];
    const float* W         = (const float*)d_in[2];
    const int*   ei        = (const int*)d_in[3];
    const int*   ej        = (const int*)d_in[4];
    float* out = (float*)d_out;

    // workspace layout (16B aligned)
    const size_t oY    = 0;                                 // 51,200,000
    const size_t oCnt  = oY + (size_t)N_NODES * 512;        // 400,000
    const size_t oOffs = oCnt + 400000;                     // 400,016 (N+1 ints, padded)
    const size_t oRank = oOffs + 400016;                    // 3,200,000
    const size_t oBsum = oRank + (size_t)N_EDGES * 4;       // 512
    const size_t oMeta = oBsum + 512;                       // 12,800,000
    const size_t total = oMeta + (size_t)N_EDGES * 16;      // ~68 MB

    char* ws = (char*)d_ws;
    const size_t yBytes = (size_t)N_NODES * 512;

    if (ws_size >= total) {
        unsigned short* Y = (unsigned short*)(ws + oY);
        int*   cnt    = (int*)(ws + oCnt);
        int*   offs   = (int*)(ws + oOffs);
        int*   rank   = (int*)(ws + oRank);
        int*   bsum   = (int*)(ws + oBsum);
        uint4* meta   = (uint4*)(ws + oMeta);

        hipMemsetAsync(cnt, 0, (size_t)N_NODES * 4, stream);
        fused_y_hist<<<YBLK + HBLK, 256, 0, stream>>>(x, W, Y, ei, ej, cnt, rank);
        scan1_kernel<<<SCAN_G, SCAN_B, 0, stream>>>(cnt, offs, bsum);
        scan23_kernel<<<SCAN_G, SCAN_B, 0, stream>>>(bsum, offs);
        scatter_kernel<<<HBLK, 256, 0, stream>>>(edge_attr, ei, ej, offs, rank, meta);
        gather_kernel<<<(4 * N_NODES + 255) / 256, 256, 0, stream>>>(offs, meta, Y, out);
    } else if (ws_size >= yBytes) {
        hipMemsetAsync(d_out, 0, (size_t)out_size * sizeof(float), stream);
        unsigned short* Y = (unsigned short*)d_ws;
        dim3 gA(NBY, 4);
        y_only_kernel<<<gA, 256, 0, stream>>>(x, W, Y);
        edge_kernel<<<HBLK, 256, 0, stream>>>(edge_attr, ei, ej, Y, out);
    } else {
        hipMemsetAsync(d_out, 0, (size_t)out_size * sizeof(float), stream);
        edge_direct<<<HBLK, 256, 0, stream>>>(x, edge_attr, W, ei, ej, out);
    }
}

// Round 6
// 176.693 us; speedup vs baseline: 1.2267x; 1.0568x over previous
//
#include <hip/hip_runtime.h>

#define N_NODES 100000
#define N_EDGES 800000
#define SCAN_B 1024
#define SCAN_G ((N_NODES + SCAN_B - 1) / SCAN_B)   // 98
#define NBY    ((N_NODES + 255) / 256)             // 391
#define YBLK   (NBY * 4)                           // 1564 y-blocks
#define HBLK   ((N_EDGES + 255) / 256)             // 3125 edge-blocks
#define OVF_CAP 65536
// Y layout: [n][kx][ky][o] bf16 (ushort), row = 16 o, plane = 256 per node (512 B)

__device__ __forceinline__ unsigned short f2bf(float f) {
    union { float f; unsigned u; } v; v.f = f;
    unsigned u = v.u;
    return (unsigned short)((u + 0x7FFFu + ((u >> 16) & 1u)) >> 16);  // RNE
}
__device__ __forceinline__ float bflo(unsigned u) {
    union { unsigned u; float f; } v; v.u = u << 16; return v.f;
}
__device__ __forceinline__ float bfhi(unsigned u) {
    union { unsigned u; float f; } v; v.u = u & 0xFFFF0000u; return v.f;
}

// ================= capacity path =================
// fused: edge blocks [0,HBLK) do hist+scatter in one pass (slot from returning
// atomic, fixed CAP stride — no scan, no rank); y blocks [HBLK,..) do the
// node transform. Edge blocks first so their atomic latency tail overlaps y.
__global__ __launch_bounds__(256) void fused_hist_scatter_y(
    const float* __restrict__ x, const float* __restrict__ W,
    unsigned short* __restrict__ Y, const float* __restrict__ edge_attr,
    const int* __restrict__ ei, const int* __restrict__ ej,
    int* __restrict__ cnt, uint4* __restrict__ meta, int cap,
    int* __restrict__ ovfCnt, int* __restrict__ ovf) {
    const int b = blockIdx.x;
    if (b < HBLK) {
        const int e = b * 256 + threadIdx.x;
        if (e >= N_EDGES) return;
        const int di = ei[e];
        const int sj = ej[e];
        if (di == sj) return;   // centerIgnore
        const float2 ea = ((const float2*)edge_attr)[e];

        float ux = fminf(fmaxf(ea.x, -1.f), 1.f);
        float uy = fminf(fmaxf(ea.y, -1.f), 1.f);
        float tx = (ux + 1.f) * 1.5f;
        float ty = (uy + 1.f) * 1.5f;
        int kx0 = min((int)tx, 2);
        int ky0 = min((int)ty, 2);
        float fx = tx - (float)kx0;
        float fy = ty - (float)ky0;
        unsigned u00 = (unsigned)((1.f - fx) * (1.f - fy) * 65535.f + 0.5f);
        unsigned u01 = (unsigned)((1.f - fx) * fy * 65535.f + 0.5f);
        unsigned u10 = (unsigned)(fx * (1.f - fy) * 65535.f + 0.5f);
        unsigned u11 = (unsigned)(fx * fy * 65535.f + 0.5f);

        const int r = atomicAdd(&cnt[di], 1);
        if (r < cap) {
            meta[(size_t)di * cap + r] =
                make_uint4(sj * 512 + (kx0 * 4 + ky0) * 32,
                           u00 | (u01 << 16), u10 | (u11 << 16), 0u);
        } else {
            const int o = atomicAdd(ovfCnt, 1);
            if (o < OVF_CAP) ovf[o] = e;
        }
    } else {
        const int bb = b - HBLK;
        const int kbase = (bb / NBY) * 4;
        const int n = (bb % NBY) * 256 + threadIdx.x;
        if (n >= N_NODES) return;

        const float4* xv = (const float4*)(x + n * 16);
        float4 a = xv[0], b2 = xv[1], c = xv[2], d = xv[3];
        float xr[16] = {a.x,a.y,a.z,a.w, b2.x,b2.y,b2.z,b2.w,
                        c.x,c.y,c.z,c.w, d.x,d.y,d.z,d.w};

        float acc[4][16];
#pragma unroll
        for (int kk = 0; kk < 4; ++kk)
#pragma unroll
            for (int o = 0; o < 16; ++o) acc[kk][o] = 0.f;

#pragma unroll
        for (int i = 0; i < 16; ++i) {
#pragma unroll
            for (int kk = 0; kk < 4; ++kk) {
                const float* wrow = W + ((kbase + kk) * 256 + i * 16);
#pragma unroll
                for (int o = 0; o < 16; ++o)
                    acc[kk][o] = fmaf(xr[i], wrow[o], acc[kk][o]);
            }
        }

        unsigned short* dst = Y + (size_t)n * 256 + kbase * 16;
#pragma unroll
        for (int kk = 0; kk < 4; ++kk) {
            unsigned pk[8];
#pragma unroll
            for (int q = 0; q < 8; ++q)
                pk[q] = (unsigned)f2bf(acc[kk][2*q]) | ((unsigned)f2bf(acc[kk][2*q+1]) << 16);
            uint4* p = (uint4*)(dst + kk * 16);
            p[0] = make_uint4(pk[0], pk[1], pk[2], pk[3]);
            p[1] = make_uint4(pk[4], pk[5], pk[6], pk[7]);
        }
    }
}

// gather (capacity layout): 4 lanes/node; per-node meta is contiguous & aligned.
__global__ __launch_bounds__(256) void gather_cap(
    const int* __restrict__ cnt, const uint4* __restrict__ meta, int cap,
    const unsigned short* __restrict__ Y, float* __restrict__ out) {
    const int g = blockIdx.x * 256 + threadIdx.x;
    const int n = g >> 2;
    const int l = g & 3;
    if (n >= N_NODES) return;
    const int t = min(cnt[n], cap);
    const uint4* mbase = meta + (size_t)n * cap;
    const char* Yb = (const char*)Y;
    const float WS = 1.f / (65535.f * 128.f);   // dequant * OUTPUT_SCALING

    float acc[16];
#pragma unroll
    for (int o = 0; o < 16; ++o) acc[o] = 0.f;

    for (int p = l; p < t; p += 4) {
        const uint4 m = mbase[p];
        const float w00 = (float)(m.y & 0xFFFFu) * WS;
        const float w01 = (float)(m.y >> 16) * WS;
        const float w10 = (float)(m.z & 0xFFFFu) * WS;
        const float w11 = (float)(m.z >> 16) * WS;

        const uint4* pA = (const uint4*)(Yb + m.x);
        const uint4* pB = (const uint4*)(Yb + m.x + 128);
        uint4 a0 = pA[0], a1 = pA[1], a2 = pA[2], a3 = pA[3];
        uint4 b0 = pB[0], b1 = pB[1], b2 = pB[2], b3 = pB[3];

        unsigned ra0[8] = {a0.x,a0.y,a0.z,a0.w, a1.x,a1.y,a1.z,a1.w};
        unsigned ra1[8] = {a2.x,a2.y,a2.z,a2.w, a3.x,a3.y,a3.z,a3.w};
        unsigned rb0[8] = {b0.x,b0.y,b0.z,b0.w, b1.x,b1.y,b1.z,b1.w};
        unsigned rb1[8] = {b2.x,b2.y,b2.z,b2.w, b3.x,b3.y,b3.z,b3.w};

#pragma unroll
        for (int q = 0; q < 8; ++q) {
            acc[2*q]   += bflo(ra0[q]) * w00 + bflo(ra1[q]) * w01
                        + bflo(rb0[q]) * w10 + bflo(rb1[q]) * w11;
            acc[2*q+1] += bfhi(ra0[q]) * w00 + bfhi(ra1[q]) * w01
                        + bfhi(rb0[q]) * w10 + bfhi(rb1[q]) * w11;
        }
    }

#pragma unroll
    for (int o = 0; o < 16; ++o) {
        acc[o] += __shfl_xor(acc[o], 1);
        acc[o] += __shfl_xor(acc[o], 2);
    }

    float4 vq;
    if      (l == 0) vq = make_float4(acc[0],  acc[1],  acc[2],  acc[3]);
    else if (l == 1) vq = make_float4(acc[4],  acc[5],  acc[6],  acc[7]);
    else if (l == 2) vq = make_float4(acc[8],  acc[9],  acc[10], acc[11]);
    else             vq = make_float4(acc[12], acc[13], acc[14], acc[15]);
    ((float4*)(out + (size_t)n * 16))[l] = vq;
}

// overflow fix-up: direct-compute the (rare) capacity-overflow edges, atomic add.
__global__ __launch_bounds__(256) void overflow_kernel(
    const int* __restrict__ ovfCnt, const int* __restrict__ ovf,
    const float* __restrict__ x, const float* __restrict__ edge_attr,
    const float* __restrict__ W, const int* __restrict__ ei,
    const int* __restrict__ ej, float* __restrict__ out) {
    const int m = min(*ovfCnt, OVF_CAP);
    for (int i = blockIdx.x * 256 + threadIdx.x; i < m; i += gridDim.x * 256) {
        const int e = ovf[i];
        const int di = ei[e];
        const int sj = ej[e];
        const float2 ea = ((const float2*)edge_attr)[e];
        float ux = fminf(fmaxf(ea.x, -1.f), 1.f);
        float uy = fminf(fmaxf(ea.y, -1.f), 1.f);
        float tx = (ux + 1.f) * 1.5f, ty = (uy + 1.f) * 1.5f;
        int kx0 = min((int)tx, 2), ky0 = min((int)ty, 2);
        float fx = tx - (float)kx0, fy = ty - (float)ky0;
        const float S = 1.f / 128.f;
        float wgt[4] = {(1.f-fx)*(1.f-fy)*S, (1.f-fx)*fy*S, fx*(1.f-fy)*S, fx*fy*S};
        int kidx[4] = {kx0*4+ky0, kx0*4+ky0+1, (kx0+1)*4+ky0, (kx0+1)*4+ky0+1};

        const float* xj = x + (size_t)sj * 16;
        float msg[16];
#pragma unroll
        for (int o = 0; o < 16; ++o) msg[o] = 0.f;
#pragma unroll
        for (int p = 0; p < 4; ++p) {
            const float* wk = W + kidx[p] * 256;
            for (int ii = 0; ii < 16; ++ii) {
                float xw = xj[ii] * wgt[p];
#pragma unroll
                for (int o = 0; o < 16; ++o)
                    msg[o] = fmaf(xw, wk[ii * 16 + o], msg[o]);
            }
        }
        float* o16 = out + (size_t)di * 16;
#pragma unroll
        for (int o = 0; o < 16; ++o) atomicAdd(o16 + o, msg[o]);
    }
}

// ================= CSR fallback path (R5) =================
__global__ __launch_bounds__(256) void fused_y_hist(
    const float* __restrict__ x, const float* __restrict__ W,
    unsigned short* __restrict__ Y, const int* __restrict__ ei,
    const int* __restrict__ ej, int* __restrict__ cnt, int* __restrict__ rank) {
    const int b = blockIdx.x;
    if (b < YBLK) {
        const int kbase = (b / NBY) * 4;
        const int n = (b % NBY) * 256 + threadIdx.x;
        if (n >= N_NODES) return;
        const float4* xv = (const float4*)(x + n * 16);
        float4 a = xv[0], bb = xv[1], c = xv[2], d = xv[3];
        float xr[16] = {a.x,a.y,a.z,a.w, bb.x,bb.y,bb.z,bb.w,
                        c.x,c.y,c.z,c.w, d.x,d.y,d.z,d.w};
        float acc[4][16];
#pragma unroll
        for (int kk = 0; kk < 4; ++kk)
#pragma unroll
            for (int o = 0; o < 16; ++o) acc[kk][o] = 0.f;
#pragma unroll
        for (int i = 0; i < 16; ++i)
#pragma unroll
            for (int kk = 0; kk < 4; ++kk) {
                const float* wrow = W + ((kbase + kk) * 256 + i * 16);
#pragma unroll
                for (int o = 0; o < 16; ++o)
                    acc[kk][o] = fmaf(xr[i], wrow[o], acc[kk][o]);
            }
        unsigned short* dst = Y + (size_t)n * 256 + kbase * 16;
#pragma unroll
        for (int kk = 0; kk < 4; ++kk) {
            unsigned pk[8];
#pragma unroll
            for (int q = 0; q < 8; ++q)
                pk[q] = (unsigned)f2bf(acc[kk][2*q]) | ((unsigned)f2bf(acc[kk][2*q+1]) << 16);
            uint4* p = (uint4*)(dst + kk * 16);
            p[0] = make_uint4(pk[0], pk[1], pk[2], pk[3]);
            p[1] = make_uint4(pk[4], pk[5], pk[6], pk[7]);
        }
    } else {
        const int e = (b - YBLK) * 256 + threadIdx.x;
        if (e >= N_EDGES) return;
        const int di = ei[e];
        if (di == ej[e]) { rank[e] = -1; return; }
        rank[e] = atomicAdd(&cnt[di], 1);
    }
}

__global__ __launch_bounds__(1024) void scan1_kernel(
    const int* __restrict__ cnt, int* __restrict__ offs, int* __restrict__ bsum) {
    const int tid = threadIdx.x;
    const int i = blockIdx.x * SCAN_B + tid;
    int v = (i < N_NODES) ? cnt[i] : 0;
    const int lane = tid & 63, wv = tid >> 6;
    int inc = v;
#pragma unroll
    for (int off = 1; off < 64; off <<= 1) {
        int t2 = __shfl_up(inc, off);
        if (lane >= off) inc += t2;
    }
    __shared__ int wsum[16], woff[16];
    if (lane == 63) wsum[wv] = inc;
    __syncthreads();
    if (tid < 16) {
        int w = wsum[tid], iw = w;
#pragma unroll
        for (int off = 1; off < 16; off <<= 1) {
            int t2 = __shfl_up(iw, off, 16);
            if (tid >= off) iw += t2;
        }
        woff[tid] = iw - w;
        if (tid == 15) bsum[blockIdx.x] = iw;
    }
    __syncthreads();
    if (i < N_NODES) offs[i] = woff[wv] + (inc - v);
}

__global__ __launch_bounds__(1024) void scan23_kernel(
    const int* __restrict__ bsum, int* __restrict__ offs) {
    const int g = blockIdx.x;
    const int tid = threadIdx.x;
    __shared__ int sprefix;
    if (tid < 64) {
        int v = 0;
        if (tid < g) v = bsum[tid];
        if (tid + 64 < g) v += bsum[tid + 64];
#pragma unroll
        for (int off = 32; off >= 1; off >>= 1) v += __shfl_xor(v, off);
        if (tid == 0) {
            sprefix = v;
            if (g == SCAN_G - 1) offs[N_NODES] = v + bsum[g];
        }
    }
    __syncthreads();
    const int i = g * SCAN_B + tid;
    if (i < N_NODES) offs[i] += sprefix;
}

__global__ __launch_bounds__(256) void scatter_kernel(
    const float* __restrict__ edge_attr, const int* __restrict__ ei,
    const int* __restrict__ ej, const int* __restrict__ offs,
    const int* __restrict__ rank, uint4* __restrict__ meta) {
    const int e = blockIdx.x * 256 + threadIdx.x;
    if (e >= N_EDGES) return;
    const int r = rank[e];
    if (r < 0) return;
    const int di = ei[e];
    const int sj = ej[e];
    const float2 ea = ((const float2*)edge_attr)[e];
    float ux = fminf(fmaxf(ea.x, -1.f), 1.f);
    float uy = fminf(fmaxf(ea.y, -1.f), 1.f);
    float tx = (ux + 1.f) * 1.5f;
    float ty = (uy + 1.f) * 1.5f;
    int kx0 = min((int)tx, 2);
    int ky0 = min((int)ty, 2);
    float fx = tx - (float)kx0;
    float fy = ty - (float)ky0;
    unsigned u00 = (unsigned)((1.f - fx) * (1.f - fy) * 65535.f + 0.5f);
    unsigned u01 = (unsigned)((1.f - fx) * fy * 65535.f + 0.5f);
    unsigned u10 = (unsigned)(fx * (1.f - fy) * 65535.f + 0.5f);
    unsigned u11 = (unsigned)(fx * fy * 65535.f + 0.5f);
    const int p = offs[di] + r;
    meta[p] = make_uint4(sj * 512 + (kx0 * 4 + ky0) * 32,
                         u00 | (u01 << 16), u10 | (u11 << 16), 0u);
}

__global__ __launch_bounds__(256) void gather_csr(
    const int* __restrict__ offs, const uint4* __restrict__ meta,
    const unsigned short* __restrict__ Y, float* __restrict__ out) {
    const int g = blockIdx.x * 256 + threadIdx.x;
    const int n = g >> 2;
    const int l = g & 3;
    if (n >= N_NODES) return;
    const int s = offs[n];
    const int t = offs[n + 1];
    const char* Yb = (const char*)Y;
    const float WS = 1.f / (65535.f * 128.f);
    float acc[16];
#pragma unroll
    for (int o = 0; o < 16; ++o) acc[o] = 0.f;
    for (int p = s + l; p < t; p += 4) {
        const uint4 m = meta[p];
        const float w00 = (float)(m.y & 0xFFFFu) * WS;
        const float w01 = (float)(m.y >> 16) * WS;
        const float w10 = (float)(m.z & 0xFFFFu) * WS;
        const float w11 = (float)(m.z >> 16) * WS;
        const uint4* pA = (const uint4*)(Yb + m.x);
        const uint4* pB = (const uint4*)(Yb + m.x + 128);
        uint4 a0 = pA[0], a1 = pA[1], a2 = pA[2], a3 = pA[3];
        uint4 b0 = pB[0], b1 = pB[1], b2 = pB[2], b3 = pB[3];
        unsigned ra0[8] = {a0.x,a0.y,a0.z,a0.w, a1.x,a1.y,a1.z,a1.w};
        unsigned ra1[8] = {a2.x,a2.y,a2.z,a2.w, a3.x,a3.y,a3.z,a3.w};
        unsigned rb0[8] = {b0.x,b0.y,b0.z,b0.w, b1.x,b1.y,b1.z,b1.w};
        unsigned rb1[8] = {b2.x,b2.y,b2.z,b2.w, b3.x,b3.y,b3.z,b3.w};
#pragma unroll
        for (int q = 0; q < 8; ++q) {
            acc[2*q]   += bflo(ra0[q]) * w00 + bflo(ra1[q]) * w01
                        + bflo(rb0[q]) * w10 + bflo(rb1[q]) * w11;
            acc[2*q+1] += bfhi(ra0[q]) * w00 + bfhi(ra1[q]) * w01
                        + bfhi(rb0[q]) * w10 + bfhi(rb1[q]) * w11;
        }
    }
#pragma unroll
    for (int o = 0; o < 16; ++o) {
        acc[o] += __shfl_xor(acc[o], 1);
        acc[o] += __shfl_xor(acc[o], 2);
    }
    float4 vq;
    if      (l == 0) vq = make_float4(acc[0],  acc[1],  acc[2],  acc[3]);
    else if (l == 1) vq = make_float4(acc[4],  acc[5],  acc[6],  acc[7]);
    else if (l == 2) vq = make_float4(acc[8],  acc[9],  acc[10], acc[11]);
    else             vq = make_float4(acc[12], acc[13], acc[14], acc[15]);
    ((float4*)(out + (size_t)n * 16))[l] = vq;
}

// last-resort fallback: per-edge direct compute
__global__ __launch_bounds__(256) void edge_direct(
    const float* __restrict__ x, const float* __restrict__ edge_attr,
    const float* __restrict__ W, const int* __restrict__ ei,
    const int* __restrict__ ej, float* __restrict__ out) {
    const int e = blockIdx.x * 256 + threadIdx.x;
    if (e >= N_EDGES) return;
    const int di = ei[e];
    const int sj = ej[e];
    const float2 ea = ((const float2*)edge_attr)[e];
    if (di == sj) return;
    float ux = fminf(fmaxf(ea.x, -1.f), 1.f);
    float uy = fminf(fmaxf(ea.y, -1.f), 1.f);
    float tx = (ux + 1.f) * 1.5f, ty = (uy + 1.f) * 1.5f;
    int kx0 = min((int)tx, 2), ky0 = min((int)ty, 2);
    float fx = tx - (float)kx0, fy = ty - (float)ky0;
    const float S = 1.f / 128.f;
    float wgt[4] = {(1.f-fx)*(1.f-fy)*S, (1.f-fx)*fy*S, fx*(1.f-fy)*S, fx*fy*S};
    int kidx[4] = {kx0*4+ky0, kx0*4+ky0+1, (kx0+1)*4+ky0, (kx0+1)*4+ky0+1};
    const float* xj = x + (size_t)sj * 16;
    float xr[16];
#pragma unroll
    for (int i = 0; i < 16; ++i) xr[i] = xj[i];
    float msg[16];
#pragma unroll
    for (int o = 0; o < 16; ++o) msg[o] = 0.f;
#pragma unroll
    for (int p = 0; p < 4; ++p) {
        const float* wk = W + kidx[p] * 256;
#pragma unroll
        for (int i = 0; i < 16; ++i) {
            float xw = xr[i] * wgt[p];
#pragma unroll
            for (int o = 0; o < 16; ++o)
                msg[o] = fmaf(xw, wk[i * 16 + o], msg[o]);
        }
    }
    float* o16 = out + (size_t)di * 16;
#pragma unroll
    for (int o = 0; o < 16; ++o) atomicAdd(o16 + o, msg[o]);
}

extern "C" void kernel_launch(void* const* d_in, const int* in_sizes, int n_in,
                              void* d_out, int out_size, void* d_ws, size_t ws_size,
                              hipStream_t stream) {
    const float* x         = (const float*)d_in[0];
    const float* edge_attr = (const float*)d_in[1];
    const float* W         = (const float*)d_in[2];
    const int*   ei        = (const int*)d_in[3];
    const int*   ej        = (const int*)d_in[4];
    float* out = (float*)d_out;
    char* ws = (char*)d_ws;

    // ---- capacity-path layout ----
    const size_t oY      = 0;                                // 51,200,000
    const size_t oCnt    = oY + (size_t)N_NODES * 512;       // 400,000
    const size_t oOvfCnt = oCnt + 400000;                    // 16
    const size_t oOvf    = oOvfCnt + 16;                     // 262,144
    const size_t oMetaC  = oOvf + (size_t)OVF_CAP * 4;       // meta (CAP*N*16)
    int cap = 0;
    if (ws_size > oMetaC)
        cap = (int)((ws_size - oMetaC) / ((size_t)N_NODES * 16));
    if (cap > 48) cap = 48;

    if (cap >= 16) {
        unsigned short* Y = (unsigned short*)(ws + oY);
        int*   cnt    = (int*)(ws + oCnt);
        int*   ovfCnt = (int*)(ws + oOvfCnt);
        int*   ovf    = (int*)(ws + oOvf);
        uint4* meta   = (uint4*)(ws + oMetaC);

        hipMemsetAsync(cnt, 0, 400016, stream);   // cnt + ovfCnt
        fused_hist_scatter_y<<<HBLK + YBLK, 256, 0, stream>>>(
            x, W, Y, edge_attr, ei, ej, cnt, meta, cap, ovfCnt, ovf);
        gather_cap<<<(4 * N_NODES + 255) / 256, 256, 0, stream>>>(cnt, meta, cap, Y, out);
        overflow_kernel<<<32, 256, 0, stream>>>(ovfCnt, ovf, x, edge_attr, W, ei, ej, out);
        return;
    }

    // ---- CSR fallback layout (R5) ----
    const size_t oOffs = oCnt + 400000;
    const size_t oRank = oOffs + 400016;
    const size_t oBsum = oRank + (size_t)N_EDGES * 4;
    const size_t oMeta = oBsum + 512;
    const size_t total = oMeta + (size_t)N_EDGES * 16;
    const size_t yBytes = (size_t)N_NODES * 512;

    if (ws_size >= total) {
        unsigned short* Y = (unsigned short*)(ws + oY);
        int*   cnt  = (int*)(ws + oCnt);
        int*   offs = (int*)(ws + oOffs);
        int*   rank = (int*)(ws + oRank);
        int*   bsum = (int*)(ws + oBsum);
        uint4* meta = (uint4*)(ws + oMeta);

        hipMemsetAsync(cnt, 0, (size_t)N_NODES * 4, stream);
        fused_y_hist<<<YBLK + HBLK, 256, 0, stream>>>(x, W, Y, ei, ej, cnt, rank);
        scan1_kernel<<<SCAN_G, SCAN_B, 0, stream>>>(cnt, offs, bsum);
        scan23_kernel<<<SCAN_G, SCAN_B, 0, stream>>>(bsum, offs);
        scatter_kernel<<<HBLK, 256, 0, stream>>>(edge_attr, ei, ej, offs, rank, meta);
        gather_csr<<<(4 * N_NODES + 255) / 256, 256, 0, stream>>>(offs, meta, Y, out);
    } else {
        hipMemsetAsync(d_out, 0, (size_t)out_size * sizeof(float), stream);
        edge_direct<<<HBLK, 256, 0, stream>>>(x, edge_attr, W, ei, ej, out);
    }
}